// Round 1
// 285.899 us; speedup vs baseline: 1.0748x; 1.0748x over previous
//
#include <hip/hip_runtime.h>

#define N0 200000
#define N1 50000
#define N2 10000
#define E1 1000000
#define E2 250000
#define CIN 128
#define HD  256

// Layer-1 buckets: 64 dsts each
#define SH1   6
#define PK1   18        // src1 < 2^18
#define NB1   782       // ceil(N1/64)
#define CAP1  2048      // mean 1279 + ~21 sigma
#define DPB1  64
// Layer-2 buckets: 16 dsts each
#define SH2   4
#define PK2   16        // src2 < 2^16
#define NB2   625       // 10000/16 exact
#define CAP2  640       // mean 400 + 12 sigma
#define DPB2  16

#define NBIN1 489       // ceil(E1/2048)
#define NBIN2 123       // ceil(E2/2048)
#define NPREP 768
#define NCVT  25000     // N0*CIN/4 / 256 exactly

// LDS edge-list capacity = bucket cap + max padding (DPB*7, rounded up)
#define EB1   (CAP1 + 512)
#define EB2   (CAP2 + 128)

typedef __attribute__((ext_vector_type(8))) short short8;
typedef __attribute__((ext_vector_type(4))) float f32x4;

__device__ __forceinline__ unsigned short f2bf(float f) {
    unsigned u = __builtin_bit_cast(unsigned, f);
    u = (u + 0x7fffu + ((u >> 16) & 1u)) >> 16;   // RNE
    return (unsigned short)u;
}
__device__ __forceinline__ float bf2f(unsigned short h) {
    unsigned u = ((unsigned)h) << 16;
    return __builtin_bit_cast(float, u);
}

// ---------------------------------------------------------------------------
// bin body: 2048 edges/block -> 1024-slot LDS bucket hist -> 1 global atomic
// per (bucket,block) -> packed (dstlow<<PACKSH | src) scatter to bucket runs.
// ---------------------------------------------------------------------------
template<int SHIFTB, int PACKSH, int CAP>
__device__ __forceinline__ void bin_body(
    int bb, const int* __restrict__ src, const int* __restrict__ dst,
    int* __restrict__ gcnt, unsigned* __restrict__ binned, int E, int* sh)
{
    int* hcnt  = sh;           // 1024
    int* hbase = sh + 1024;    // 1024
    int* hcur  = sh + 2048;    // 1024
    const int t = threadIdx.x;
    #pragma unroll
    for (int j = 0; j < 4; j++) hcnt[t + j * 256] = 0;
    __syncthreads();

    unsigned pk[8];
    int      bk[8];
    const int e0 = bb * 2048;
    #pragma unroll
    for (int j = 0; j < 8; j++) {
        const int e = e0 + j * 256 + t;
        if (e < E) {
            const int d = dst[e];
            const int s = src[e];
            bk[j] = d >> SHIFTB;
            pk[j] = ((unsigned)(d & ((1 << SHIFTB) - 1)) << PACKSH) | (unsigned)s;
            atomicAdd(&hcnt[bk[j]], 1);
        } else bk[j] = -1;
    }
    __syncthreads();

    #pragma unroll
    for (int j = 0; j < 4; j++) {
        const int i = t + j * 256;
        hbase[i] = atomicAdd(&gcnt[i], hcnt[i]);
        hcur[i]  = 0;
    }
    __syncthreads();

    #pragma unroll
    for (int j = 0; j < 8; j++) {
        if (bk[j] >= 0) {
            const int idx = atomicAdd(&hcur[bk[j]], 1);
            binned[(size_t)bk[j] * CAP + hbase[bk[j]] + idx] = pk[j];
        }
    }
}

// ---------------------------------------------------------------------------
// Mega-kernel A: bin1 | bin2 | weight-swizzle | x->bf16 convert | zero sentinels
// ---------------------------------------------------------------------------
__global__ __launch_bounds__(256) void megaA_kernel(
    const float* __restrict__ x, unsigned short* __restrict__ xb,
    unsigned short* __restrict__ hb,
    const float* __restrict__ Wl1, const float* __restrict__ Wr1,
    const float* __restrict__ Wl2, const float* __restrict__ Wr2,
    unsigned short* __restrict__ wsw1, unsigned short* __restrict__ wsw2,
    const int* __restrict__ src1, const int* __restrict__ dst1,
    const int* __restrict__ src2, const int* __restrict__ dst2,
    int* __restrict__ gcnt1, int* __restrict__ gcnt2,
    unsigned* __restrict__ binned1, unsigned* __restrict__ binned2)
{
    __shared__ int sh[3072];
    const int b = blockIdx.x;
    const int t = threadIdx.x;

    if (b < NBIN1) {
        bin_body<SH1, PK1, CAP1>(b, src1, dst1, gcnt1, binned1, E1, sh);
    } else if (b < NBIN1 + NBIN2) {
        bin_body<SH2, PK2, CAP2>(b - NBIN1, src2, dst2, gcnt2, binned2, E2, sh);
    } else if (b < NBIN1 + NBIN2 + NPREP) {
        const int pb = b - NBIN1 - NBIN2;
        const float* Wl; const float* Wr; unsigned short* wsw; int K, tid;
        if (pb < 256) { Wl = Wl1; Wr = Wr1; wsw = wsw1; K = CIN; tid = pb * 256 + t; }
        else          { Wl = Wl2; Wr = Wr2; wsw = wsw2; K = HD;  tid = (pb - 256) * 256 + t; }
        const int j  = tid & 7;
        const int L  = (tid >> 3) & 63;
        const int nt = (tid >> 9) & 15;
        const int kt = tid >> 13;
        const int k  = kt * 32 + (L >> 4) * 8 + j;
        const int n  = nt * 16 + (L & 15);
        const float v = (k < K) ? Wl[(size_t)k * HD + n]
                                : Wr[(size_t)(k - K) * HD + n];
        wsw[tid] = f2bf(v);
    } else if (b < NBIN1 + NBIN2 + NPREP + NCVT) {
        const int i = (b - NBIN1 - NBIN2 - NPREP) * 256 + t;   // exact cover
        const float4 v = ((const float4*)x)[i];
        ushort4 o;
        o.x = f2bf(v.x); o.y = f2bf(v.y); o.z = f2bf(v.z); o.w = f2bf(v.w);
        ((ushort4*)xb)[i] = o;
    } else {
        // zero the sentinel rows used for list padding
        if (t < 64)  ((unsigned*)(xb + (size_t)N0 * CIN))[t] = 0u;   // 256 B
        if (t < 128) ((unsigned*)(hb + (size_t)N1 * HD))[t]  = 0u;   // 512 B
    }
}

// ---------------------------------------------------------------------------
// Layer-1 mega: one block per 64-dst bucket, 512 threads (8 waves).
//  A) CSR-finalize bucket in LDS, lists padded to x8 with sentinel row N0
//  B) gather-mean: quarter-wave (16 lanes x short8 = 128 cols) per row,
//     4 rows in flight per wave, remainder-free 8-deep batches
//  C) 4 m-tiles x 2 n-halves GEMM -> hb = relu(.. + b1), bf16
// ---------------------------------------------------------------------------
__global__ __launch_bounds__(512) void layer1_mega(
    const unsigned short* __restrict__ xb,
    const unsigned* __restrict__ binned1, const int* __restrict__ gcnt1,
    const unsigned short* __restrict__ wsw1, const float* __restrict__ bias,
    unsigned short* __restrict__ hb)
{
    __shared__ int ebuf[EB1];
    __shared__ int lhist[DPB1], loff[DPB1], lcur[DPB1];
    __shared__ __align__(16) unsigned short aggT[4 * DPB1 * 4 * 8];  // 16 KB

    const int t = threadIdx.x;
    const int b = blockIdx.x;
    const int cnt = gcnt1[b];
    const unsigned* bp = binned1 + (size_t)b * CAP1;

    // ---- A: bucket CSR in LDS (padded offsets, raw counts kept in lhist)
    if (t < DPB1) lhist[t] = 0;
    __syncthreads();
    for (int i = t; i < cnt; i += 512)
        atomicAdd(&lhist[bp[i] >> PK1], 1);
    __syncthreads();
    if (t < DPB1) {                      // single-wave shfl prefix scan
        const int p = (lhist[t] + 7) & ~7;
        int sum = p;
        #pragma unroll
        for (int ofs = 1; ofs < DPB1; ofs <<= 1) {
            const int u = __shfl_up(sum, ofs);
            if (t >= ofs) sum += u;
        }
        const int st = sum - p;
        loff[t] = st; lcur[t] = st;
    }
    __syncthreads();
    for (int i = t; i < cnt; i += 512) {
        const unsigned p = bp[i];
        const int slot = atomicAdd(&lcur[p >> PK1], 1);
        ebuf[slot] = (int)(p & ((1u << PK1) - 1u));
    }
    __syncthreads();
    if (t < DPB1) {                      // pad each list to x8 with sentinel
        const int h = lhist[t];
        const int np = (h + 7) & ~7;
        const int s0 = loff[t];
        for (int i = s0 + h; i < s0 + np; i++) ebuf[i] = N0;
    }
    __syncthreads();

    // ---- B: gather. quarter-wave per row, 2 sequential rounds of 4 rows/wave
    const int w = t >> 6, L = t & 63;
    const int qd = L >> 4, l16 = L & 15;
    const unsigned short* xp = xb + (size_t)l16 * 8;
    #pragma unroll 1
    for (int rr = 0; rr < 2; rr++) {
        const int r = w * 8 + rr * 4 + qd;
        const int base = loff[r];
        const int n    = lhist[r];
        const int npad = (n + 7) & ~7;
        float acc[8];
        #pragma unroll
        for (int j = 0; j < 8; j++) acc[j] = 0.f;
        for (int i = 0; i < npad; i += 8) {
            short8 v[8];
            #pragma unroll
            for (int u = 0; u < 8; u++) {
                const int s = ebuf[base + i + u];
                v[u] = *(const short8*)(xp + (size_t)s * CIN);
            }
            #pragma unroll
            for (int u = 0; u < 8; u++) {
                #pragma unroll
                for (int j = 0; j < 8; j++)
                    acc[j] += bf2f((unsigned short)v[u][j]);
            }
        }
        const float sc = 1.0f / fmaxf((float)n, 1.0f);
        short8 o;
        #pragma unroll
        for (int j = 0; j < 8; j++) o[j] = (short)f2bf(acc[j] * sc);
        const int kt = l16 >> 2, q = l16 & 3;     // col = kt*32 + q*8 + j
        *(short8*)&aggT[((kt * DPB1 + r) * 4 + q) * 8] = o;
    }
    __syncthreads();

    // ---- C: GEMM. wave w: m-tile (w&3), n-half (w>>2)
    const int m = L & 15, q = L >> 4;
    const int mt = w & 3, nh = w >> 2;
    const int row_l = mt * 16 + m;
    const int rg2 = min(b * DPB1 + row_l, N1 - 1);
    const unsigned short* a2p = xb + (size_t)rg2 * CIN + q * 8;

    f32x4 acc[8];
    #pragma unroll
    for (int nt = 0; nt < 8; nt++) acc[nt] = (f32x4){0.f, 0.f, 0.f, 0.f};

    #pragma unroll
    for (int kt = 0; kt < 8; kt++) {
        short8 af;
        if (kt < 4) af = *(const short8*)&aggT[((kt * DPB1 + row_l) * 4 + q) * 8];
        else        af = *(const short8*)(a2p + (kt - 4) * 32);
        #pragma unroll
        for (int nt = 0; nt < 8; nt++) {
            const short8 bf = *(const short8*)(
                wsw1 + (((size_t)kt * 16 + (nh * 8 + nt)) * 64 + L) * 8);
            acc[nt] = __builtin_amdgcn_mfma_f32_16x16x32_bf16(af, bf, acc[nt], 0, 0, 0);
        }
    }

    const int orow0 = b * DPB1 + mt * 16 + q * 4;
    #pragma unroll
    for (int nt = 0; nt < 8; nt++) {
        const int col = (nh * 8 + nt) * 16 + m;
        const float bv = bias[col];
        #pragma unroll
        for (int r = 0; r < 4; r++) {
            const int row = orow0 + r;
            if (row < N1) {
                const float v = fmaxf(acc[nt][r] + bv, 0.0f);
                hb[(size_t)row * HD + col] = f2bf(v);
            }
        }
    }
}

// ---------------------------------------------------------------------------
// Layer-2 mega: one block per 16-dst bucket, 512 threads. N2 = 625*16 exact.
//  B) half-wave (32 lanes x short8 = 256 cols) per row, 2 rows/wave,
//     remainder-free 8-deep batches (lists padded with sentinel row N1)
//  C) 1 m-tile, 8 waves x 2 n-tiles; fp32 out + bias, no relu.
// ---------------------------------------------------------------------------
__global__ __launch_bounds__(512) void layer2_mega(
    const unsigned short* __restrict__ hb,
    const unsigned* __restrict__ binned2, const int* __restrict__ gcnt2,
    const unsigned short* __restrict__ wsw2, const float* __restrict__ bias,
    float* __restrict__ outp)
{
    __shared__ int ebuf[EB2];
    __shared__ int lhist[DPB2], loff[DPB2], lcur[DPB2];
    __shared__ __align__(16) unsigned short aggT[8 * DPB2 * 4 * 8];   // 8 KB

    const int t = threadIdx.x;
    const int b = blockIdx.x;
    const int cnt = gcnt2[b];
    const unsigned* bp = binned2 + (size_t)b * CAP2;

    if (t < DPB2) lhist[t] = 0;
    __syncthreads();
    for (int i = t; i < cnt; i += 512)
        atomicAdd(&lhist[bp[i] >> PK2], 1);
    __syncthreads();
    if (t < DPB2) {                      // lanes 0-15 of wave 0: shfl scan
        const int p = (lhist[t] + 7) & ~7;
        int sum = p;
        #pragma unroll
        for (int ofs = 1; ofs < DPB2; ofs <<= 1) {
            const int u = __shfl_up(sum, ofs);
            if (t >= ofs) sum += u;
        }
        const int st = sum - p;
        loff[t] = st; lcur[t] = st;
    }
    __syncthreads();
    for (int i = t; i < cnt; i += 512) {
        const unsigned p = bp[i];
        const int slot = atomicAdd(&lcur[p >> PK2], 1);
        ebuf[slot] = (int)(p & 0xFFFFu);
    }
    __syncthreads();
    if (t < DPB2) {
        const int h = lhist[t];
        const int np = (h + 7) & ~7;
        const int s0 = loff[t];
        for (int i = s0 + h; i < s0 + np; i++) ebuf[i] = N1;
    }
    __syncthreads();

    // ---- B: half-wave per row, 16 rows = 8 waves x 2, single round
    const int w = t >> 6, L = t & 63;
    const int hf = L >> 5, l32 = L & 31;
    {
        const int r = w * 2 + hf;
        const int base = loff[r];
        const int n    = lhist[r];
        const int npad = (n + 7) & ~7;
        float acc[8];
        #pragma unroll
        for (int j = 0; j < 8; j++) acc[j] = 0.f;
        const unsigned short* hp = hb + (size_t)l32 * 8;
        for (int i = 0; i < npad; i += 8) {
            short8 v[8];
            #pragma unroll
            for (int u = 0; u < 8; u++) {
                const int s = ebuf[base + i + u];
                v[u] = *(const short8*)(hp + (size_t)s * HD);
            }
            #pragma unroll
            for (int u = 0; u < 8; u++) {
                #pragma unroll
                for (int j = 0; j < 8; j++)
                    acc[j] += bf2f((unsigned short)v[u][j]);
            }
        }
        const float sc = 1.0f / fmaxf((float)n, 1.0f);
        short8 o;
        #pragma unroll
        for (int j = 0; j < 8; j++) o[j] = (short)f2bf(acc[j] * sc);
        const int kt = l32 >> 2, q = l32 & 3;     // col = kt*32 + q*8 + j
        *(short8*)&aggT[((kt * DPB2 + r) * 4 + q) * 8] = o;
    }
    __syncthreads();

    // C: single m-tile; wave w covers n-tiles 2w, 2w+1
    const int m = L & 15, q = L >> 4;
    const int rg2 = b * DPB2 + m;          // exact, no tail
    const unsigned short* a2p = hb + (size_t)rg2 * HD + q * 8;

    f32x4 acc[2];
    acc[0] = (f32x4){0.f, 0.f, 0.f, 0.f};
    acc[1] = (f32x4){0.f, 0.f, 0.f, 0.f};

    #pragma unroll
    for (int kt = 0; kt < 16; kt++) {
        short8 af;
        if (kt < 8) af = *(const short8*)&aggT[((kt * DPB2 + m) * 4 + q) * 8];
        else        af = *(const short8*)(a2p + (kt - 8) * 32);
        #pragma unroll
        for (int nt = 0; nt < 2; nt++) {
            const short8 bf = *(const short8*)(
                wsw2 + (((size_t)kt * 16 + (w * 2 + nt)) * 64 + L) * 8);
            acc[nt] = __builtin_amdgcn_mfma_f32_16x16x32_bf16(af, bf, acc[nt], 0, 0, 0);
        }
    }

    const int orow0 = b * DPB2 + q * 4;
    #pragma unroll
    for (int nt = 0; nt < 2; nt++) {
        const int col = (w * 2 + nt) * 16 + m;
        const float bv = bias[col];
        #pragma unroll
        for (int r = 0; r < 4; r++)
            outp[(size_t)(orow0 + r) * HD + col] = acc[nt][r] + bv;
    }
}

extern "C" void kernel_launch(void* const* d_in, const int* in_sizes, int n_in,
                              void* d_out, int out_size, void* d_ws, size_t ws_size,
                              hipStream_t stream)
{
    const float* x    = (const float*)d_in[0];
    const int*   src1 = (const int*)  d_in[1];
    const int*   dst1 = (const int*)  d_in[2];
    const int*   src2 = (const int*)  d_in[3];
    const int*   dst2 = (const int*)  d_in[4];
    const float* Wl1  = (const float*)d_in[5];
    const float* Wr1  = (const float*)d_in[6];
    const float* b1   = (const float*)d_in[7];
    const float* Wl2  = (const float*)d_in[8];
    const float* Wr2  = (const float*)d_in[9];
    const float* b2   = (const float*)d_in[10];
    float* out = (float*)d_out;

    // ---- workspace (~86 MB): xb(+1 row) | hb(+1 row) | wsw1 | wsw2 | gcnt | binned1 | binned2
    unsigned short* xb   = (unsigned short*)d_ws;
    unsigned short* hb   = xb + (size_t)(N0 + 1) * CIN;
    unsigned short* wsw1 = hb + (size_t)(N1 + 1) * HD;
    unsigned short* wsw2 = wsw1 + 2 * CIN * HD;
    int* gcnt1 = (int*)(wsw2 + 2 * HD * HD);        // 1024
    int* gcnt2 = gcnt1 + 1024;                      // 1024
    unsigned* binned1 = (unsigned*)(gcnt2 + 1024);  // NB1*CAP1
    unsigned* binned2 = binned1 + (size_t)NB1 * CAP1;

    hipMemsetAsync(gcnt1, 0, 2048 * sizeof(int), stream);

    megaA_kernel<<<NBIN1 + NBIN2 + NPREP + NCVT + 1, 256, 0, stream>>>(
        x, xb, hb, Wl1, Wr1, Wl2, Wr2, wsw1, wsw2,
        src1, dst1, src2, dst2, gcnt1, gcnt2, binned1, binned2);

    layer1_mega<<<NB1, 512, 0, stream>>>(xb, binned1, gcnt1, wsw1, b1, hb);
    layer2_mega<<<NB2, 512, 0, stream>>>(hb, binned2, gcnt2, wsw2, b2, out);
}